// Round 5
// baseline (333.542 us; speedup 1.0000x reference)
//
#include <hip/hip_runtime.h>
#include <math.h>

#define DCOLS 128
#define ROUTIT 6
#define EPS_N 1e-12f
#define EPP 4       // edges per wave pass (16 lanes per edge)
#define NCACHE 4    // passes with z register-cached (16 edges)

__device__ __forceinline__ float shflx(float v, int mask) {
    return __shfl_xor(v, mask, 64);
}

// L2-normalize an 8-float chunk; capsule = 16 flat cols = 2 adjacent lanes.
__device__ __forceinline__ void norm8(float v[8]) {
    float sq = v[0] * v[0];
#pragma unroll
    for (int q = 1; q < 8; ++q) sq = fmaf(v[q], v[q], sq);
    sq += shflx(sq, 1);
    float inv = 1.0f / fmaxf(sqrtf(sq), EPS_N);
#pragma unroll
    for (int q = 0; q < 8; ++q) v[q] *= inv;
}

__device__ __forceinline__ void load8(const float* __restrict__ base, float v[8]) {
    const float4* p = reinterpret_cast<const float4*>(base);
    float4 a = p[0], b = p[1];
    v[0] = a.x; v[1] = a.y; v[2] = a.z; v[3] = a.w;
    v[4] = b.x; v[5] = b.y; v[6] = b.z; v[7] = b.w;
}

// Fused count + within-node position (single atomic pass).
__global__ void count_pos_kernel(const int* __restrict__ trg, int* __restrict__ cnt,
                                 int* __restrict__ pos, int m) {
    int e = blockIdx.x * blockDim.x + threadIdx.x;
    if (e < m) pos[e] = atomicAdd(&cnt[trg[e]], 1);
}

// Single-block exclusive scan: cnt[0..n) -> offsets[0..n].
__global__ void scan_kernel(const int* __restrict__ cnt, int* __restrict__ offsets,
                            int n, int m) {
    __shared__ int part[1024];
    int tid = threadIdx.x;
    if (tid == 0) offsets[n] = m;
    int chunk = (n + 1023) / 1024;
    int lo = tid * chunk;
    int hi = min(lo + chunk, n);
    int s = 0;
    for (int i = lo; i < hi; ++i) s += cnt[i];
    part[tid] = s;
    __syncthreads();
    for (int off = 1; off < 1024; off <<= 1) {
        int t = (tid >= off) ? part[tid - off] : 0;
        __syncthreads();
        part[tid] += t;
        __syncthreads();
    }
    int run = (tid > 0) ? part[tid - 1] : 0;
    for (int i = lo; i < hi; ++i) {
        int c = cnt[i];
        offsets[i] = run;
        run += c;
    }
}

// Non-atomic placement: elist[offsets[trg]+pos] = src.
__global__ void place_kernel(const int* __restrict__ src, const int* __restrict__ trg,
                             const int* __restrict__ pos, const int* __restrict__ offsets,
                             int* __restrict__ elist, int m) {
    int e = blockIdx.x * blockDim.x + threadIdx.x;
    if (e < m) elist[offsets[trg[e]] + pos[e]] = src[e];
}

// One edge slot: z[8] = lane's 8 flat cols of the (normalized) source row.
// Sn[q] = S value for this lane's q-th col. p-reduce over the capsule's 2
// lanes (mask 1), softmax-sum over the 8 capsules (masks 2,4,8).
// No max-subtraction: |p| <= 32 (unit capsules, |S[j]| <= 8), exp safe in f32.
__device__ __forceinline__ void process_edge(const float z[8], const float Sn[8],
                                             float acc[8], bool valid) {
    float part = z[0] * Sn[0];
#pragma unroll
    for (int q = 1; q < 8; ++q) part = fmaf(z[q], Sn[q], part);
    float p = part + shflx(part, 1);
    float ex = __expf(p);
    float zs = ex;
    zs += shflx(zs, 2); zs += shflx(zs, 4); zs += shflx(zs, 8);
    float w = valid ? ex * __builtin_amdgcn_rcpf(zs) : 0.0f;
#pragma unroll
    for (int q = 0; q < 8; ++q) acc[q] = fmaf(w, z[q], acc[q]);
}

// Wave per node. lane = 16*slot + l16. Lane owns FLAT cols 8*l16..8*l16+7.
// S[l16] is lane-local; p-term for flat col f uses S[f & 15].
// Reads RAW x and normalizes on load (reference's xnorm recomputed in place).
__global__ __launch_bounds__(256) void routing_kernel(
    const float* __restrict__ x, const int* __restrict__ offsets,
    const int* __restrict__ elist, float* __restrict__ out, int n)
{
    int node = (int)((blockIdx.x * blockDim.x + threadIdx.x) >> 6);
    int lane = threadIdx.x & 63;
    if (node >= n) return;
    int l16 = lane & 15;
    int slot = lane >> 4;

    float xv[8];
    load8(x + (size_t)node * DCOLS + 8 * l16, xv);
    norm8(xv);
    float cc[8];
#pragma unroll
    for (int q = 0; q < 8; ++q) cc[q] = xv[q];

    int e0 = offsets[node];
    int e1 = offsets[node + 1];
    int deg = e1 - e0;

    // z register cache: first NCACHE*EPP edges, normalized once, reused 6x.
    float zc[NCACHE][8];
#pragma unroll
    for (int pp = 0; pp < NCACHE; ++pp) {
        if (pp * EPP < deg) {  // wave-uniform
            int eidx = e0 + pp * EPP + slot;
            int u = (eidx < e1) ? elist[eidx] : node;
            load8(x + (size_t)u * DCOLS + 8 * l16, zc[pp]);
            norm8(zc[pp]);
        }
    }

    int src_base = (lane & ~15) | (8 * (l16 & 1));

    for (int t = 0; t < ROUTIT; ++t) {
        // S[l16] lane-local, then broadcast the 8 values this lane needs
        float Sl = ((cc[0] + cc[1]) + (cc[2] + cc[3])) + ((cc[4] + cc[5]) + (cc[6] + cc[7]));
        float Sn[8];
#pragma unroll
        for (int q = 0; q < 8; ++q) Sn[q] = __shfl(Sl, src_base + q, 64);

        float acc[8];
#pragma unroll
        for (int q = 0; q < 8; ++q) acc[q] = 0.0f;

#pragma unroll
        for (int pp = 0; pp < NCACHE; ++pp) {
            if (pp * EPP < deg) {
                bool valid = (e0 + pp * EPP + slot) < e1;
                process_edge(zc[pp], Sn, acc, valid);
            }
        }
        // streaming tail for high-degree nodes (~3% of edge-visits)
        for (int eb = e0 + NCACHE * EPP; eb < e1; eb += EPP) {
            int eidx = eb + slot;
            int u = (eidx < e1) ? elist[eidx] : node;
            float z[8];
            load8(x + (size_t)u * DCOLS + 8 * l16, z);
            norm8(z);
            process_edge(z, Sn, acc, eidx < e1);
        }

        // reduce across the 4 edge slots
#pragma unroll
        for (int q = 0; q < 8; ++q) {
            acc[q] += shflx(acc[q], 16);
            acc[q] += shflx(acc[q], 32);
        }
#pragma unroll
        for (int q = 0; q < 8; ++q) cc[q] = acc[q] + xv[q];

        if (t < ROUTIT - 1) norm8(cc);
    }

    if (slot == 0) {
        float4* orow = reinterpret_cast<float4*>(out + (size_t)node * DCOLS + 8 * l16);
        orow[0] = make_float4(cc[0], cc[1], cc[2], cc[3]);
        orow[1] = make_float4(cc[4], cc[5], cc[6], cc[7]);
    }
}

extern "C" void kernel_launch(void* const* d_in, const int* in_sizes, int n_in,
                              void* d_out, int out_size, void* d_ws, size_t ws_size,
                              hipStream_t stream) {
    const float* x = (const float*)d_in[0];
    const int* ei = (const int*)d_in[1];
    float* out = (float*)d_out;
    int n = in_sizes[0] / DCOLS;
    int m = in_sizes[1] / 2;
    const int* src = ei;
    const int* trg = ei + m;

    char* ws = (char*)d_ws;
    int* offsets = (int*)ws;      ws += (size_t)(n + 1) * sizeof(int);
    int* cnt = (int*)ws;          ws += (size_t)n * sizeof(int);
    int* pos = (int*)ws;          ws += (size_t)m * sizeof(int);
    int* elist = (int*)ws;        ws += (size_t)m * sizeof(int);

    (void)hipMemsetAsync(cnt, 0, (size_t)n * sizeof(int), stream);

    count_pos_kernel<<<(m + 255) / 256, 256, 0, stream>>>(trg, cnt, pos, m);
    scan_kernel<<<1, 1024, 0, stream>>>(cnt, offsets, n, m);
    place_kernel<<<(m + 255) / 256, 256, 0, stream>>>(src, trg, pos, offsets, elist, m);
    routing_kernel<<<(n + 3) / 4, 256, 0, stream>>>(x, offsets, elist, out, n);
}